// Round 1
// baseline (282.378 us; speedup 1.0000x reference)
//
#include <hip/hip_runtime.h>

#define D 1024
#define EPS 1e-5f

// 256 threads = 4 waves. Each WAVE independently processes one token per
// grid-stride iteration:
//   - code table staged into LDS once per BLOCK (not per token)
//   - LayerNorm reduction is a pure in-register 64-lane shfl_xor butterfly
//     (no LDS round-trip, zero per-token __syncthreads)
// Lane l handles elements {k*256 + 4l .. k*256 + 4l+3}, k=0..3, so every
// int4/float4 load/store instruction covers 1 KiB contiguous (fully coalesced).
__global__ __launch_bounds__(256) void emb_deq_ln_kernel(
    const int*   __restrict__ x,       // [T] token ids
    const int*   __restrict__ w,       // [V, D] int codes 0..255 (int32 each)
    const float* __restrict__ absmax,  // [V*D/4096]; row v uses absmax[v>>2]
    const float* __restrict__ code,    // [256]
    const float* __restrict__ ln_w,    // [D]
    const float* __restrict__ ln_b,    // [D]
    float*       __restrict__ out,     // [T, D]
    const int    T)
{
    __shared__ float code_s[256];
    code_s[threadIdx.x] = code[threadIdx.x];
    __syncthreads();  // only barrier in the kernel

    const int lane = threadIdx.x & 63;
    const int wid  = threadIdx.x >> 6;
    const int wave_global = blockIdx.x * 4 + wid;
    const int nwave       = gridDim.x * 4;

    for (int t = wave_global; t < T; t += nwave) {
        const int   v     = x[t];
        const float scale = absmax[v >> 2];
        const int4* __restrict__ wr = (const int4*)(w + (size_t)v * D);

        // 4 x 1KiB contiguous loads; all 4 in flight together (MLP).
        const int4 q0 = wr[lane];
        const int4 q1 = wr[64  + lane];
        const int4 q2 = wr[128 + lane];
        const int4 q3 = wr[192 + lane];

        float vals[16];
        vals[0]  = code_s[q0.x]; vals[1]  = code_s[q0.y];
        vals[2]  = code_s[q0.z]; vals[3]  = code_s[q0.w];
        vals[4]  = code_s[q1.x]; vals[5]  = code_s[q1.y];
        vals[6]  = code_s[q1.z]; vals[7]  = code_s[q1.w];
        vals[8]  = code_s[q2.x]; vals[9]  = code_s[q2.y];
        vals[10] = code_s[q2.z]; vals[11] = code_s[q2.w];
        vals[12] = code_s[q3.x]; vals[13] = code_s[q3.y];
        vals[14] = code_s[q3.z]; vals[15] = code_s[q3.w];

        float s = 0.0f, ss = 0.0f;
        #pragma unroll
        for (int i = 0; i < 16; ++i) {
            const float f = vals[i] * scale;
            vals[i] = f;
            s  += f;
            ss  = fmaf(f, f, ss);
        }

        // 64-lane butterfly: every lane ends with the full sums.
        #pragma unroll
        for (int m = 32; m > 0; m >>= 1) {
            s  += __shfl_xor(s,  m, 64);
            ss += __shfl_xor(ss, m, 64);
        }

        const float mean = s * (1.0f / D);
        const float rstd = rsqrtf(fmaf(-mean, mean, ss * (1.0f / D)) + EPS);

        float* __restrict__ op = out + (size_t)t * D;
        #pragma unroll
        for (int k = 0; k < 4; ++k) {
            const float4 lw = ((const float4*)ln_w)[k * 64 + lane];
            const float4 lb = ((const float4*)ln_b)[k * 64 + lane];
            float4 o;
            o.x = (vals[k * 4 + 0] - mean) * rstd * lw.x + lb.x;
            o.y = (vals[k * 4 + 1] - mean) * rstd * lw.y + lb.y;
            o.z = (vals[k * 4 + 2] - mean) * rstd * lw.z + lb.z;
            o.w = (vals[k * 4 + 3] - mean) * rstd * lw.w + lb.w;
            ((float4*)op)[k * 64 + lane] = o;
        }
    }
}

extern "C" void kernel_launch(void* const* d_in, const int* in_sizes, int n_in,
                              void* d_out, int out_size, void* d_ws, size_t ws_size,
                              hipStream_t stream) {
    const int*   x      = (const int*)d_in[0];
    const int*   w      = (const int*)d_in[1];
    const float* absmax = (const float*)d_in[2];
    const float* code   = (const float*)d_in[3];
    const float* ln_w   = (const float*)d_in[4];
    const float* ln_b   = (const float*)d_in[5];
    float* out = (float*)d_out;

    const int T = in_sizes[0];  // 16384 tokens

    // 4 tokens per block per sweep; cap grid at 2048 blocks (8 blocks/CU
    // budget on 256 CUs) and grid-stride the rest (2 tokens/wave at T=16384).
    int blocks = (T + 3) / 4;
    if (blocks > 2048) blocks = 2048;

    emb_deq_ln_kernel<<<blocks, 256, 0, stream>>>(x, w, absmax, code, ln_w, ln_b, out, T);
}